// Round 10
// baseline (101.156 us; speedup 1.0000x reference)
//
#include <hip/hip_runtime.h>
#include <stdint.h>

#define UNITS  4096
#define SEG    96         // per-wave list segment; wave window count 60.5 +- 7.55 -> +4.8 sigma
#define CAP    (4 * SEG)  // 384
#define NSLOT  6          // CAP/64
#define LOF    0.44f      // theta ~= 0.5244 +- 0.0206 ; [LO,HI) = +-4.1 sigma
#define HIF    0.61f
#define SELBITS 22        // bits(0.61f)-bits(0.44f) = 0x3AE148 < 2^22

// LDS-only barrier (no vmcnt drain)
__device__ __forceinline__ void lds_barrier() {
    asm volatile("s_waitcnt lgkmcnt(0)" ::: "memory");
    __builtin_amdgcn_s_barrier();
}
__device__ __forceinline__ uint32_t flipu(uint32_t b) {
    return b ^ (uint32_t)(((int32_t)b >> 31) | (int32_t)0x80000000);
}
// popcount of mask bits strictly below this lane
__device__ __forceinline__ uint32_t mbcnt64(uint64_t m) {
    return __builtin_amdgcn_mbcnt_hi((uint32_t)(m >> 32),
           __builtin_amdgcn_mbcnt_lo((uint32_t)m, 0u));
}

// One block (256 threads) per row.
// Single fused pass: window ballots + scatter into per-wave fixed segments
// (no atomics, no pre-barrier). ONE barrier. Then all 4 waves redundantly
// radix-select rank (k - cb) over rebased 22-bit keys, 2 bits per round.
// Bracket + segment-overflow verified per row; failures take the exact
// block-wide 32-bit bit-search fallback.
__global__ __launch_bounds__(256, 8) void ksparse_select_kernel(
        const float* __restrict__ X, float* __restrict__ out, int kidx) {
    __shared__ uint32_t list[CAP];  // 1.5 KiB, segmented per wave
    __shared__ uint32_t wnb[4];     // per-wave count below LO
    __shared__ uint32_t wc[4];      // per-wave window count (may exceed SEG)
    __shared__ uint32_t fbc[4];     // fallback per-wave counts

    const int t    = threadIdx.x;
    const int w    = t >> 6;
    const int lane = t & 63;

    // load row (coalesced float4)
    float f[16];
    {
        const float4* Xv = reinterpret_cast<const float4*>(X + (size_t)blockIdx.x * UNITS);
#pragma unroll
        for (int j = 0; j < 4; ++j) {
            float4 v = Xv[j * 256 + t];
            f[4*j] = v.x; f[4*j+1] = v.y; f[4*j+2] = v.z; f[4*j+3] = v.w;
        }
    }

    // fused window-count + segment scatter (single pass, no atomics)
    const uint32_t LOu = __float_as_uint(LOF);
    uint32_t nbw = 0, pfx = 0;
#pragma unroll
    for (int e = 0; e < 16; ++e) {
        const bool lo = f[e] < LOF;
        const bool hi = f[e] < HIF;
        const uint64_t mlo  = __ballot(lo);
        const uint64_t mwin = __ballot(hi && !lo);
        nbw += (uint32_t)__popcll(mlo);
        if (hi && !lo) {
            const uint32_t off = pfx + mbcnt64(mwin);
            if (off < SEG) list[SEG * w + off] = __float_as_uint(f[e]) - LOu;
        }
        pfx += (uint32_t)__popcll(mwin);
    }
    if (lane == 0) { wnb[w] = nbw; wc[w] = pfx; }

    lds_barrier();  // list + wnb + wc visible (the ONLY fast-path barrier)

    const uint32_t c0 = wc[0], c1 = wc[1], c2 = wc[2], c3 = wc[3];
    const uint32_t c  = c0 + c1 + c2 + c3;
    const uint32_t cb = wnb[0] + wnb[1] + wnb[2] + wnb[3];
    const uint32_t k  = (uint32_t)kidx;
    const uint32_t mx = max(max(c0, c1), max(c2, c3));

    float4* Ov = reinterpret_cast<float4*>(out + (size_t)blockIdx.x * UNITS);

    if (cb <= k && k < cb + c && mx <= SEG) {   // block-uniform bracket check
        const uint32_t r = k - cb;              // rank of theta within the window

        // distributed list load, static (seg, off) map per slot, sentinel-padded
        uint32_t sv[NSLOT];
        {
            const bool loh = lane < 32;
            uint32_t segi[NSLOT], offi[NSLOT];
            segi[0] = 0;             offi[0] = lane;
            segi[1] = loh ? 0 : 1;   offi[1] = loh ? 64 + lane : lane - 32;
            segi[2] = 1;             offi[2] = 32 + lane;
            segi[3] = 2;             offi[3] = lane;
            segi[4] = loh ? 2 : 3;   offi[4] = loh ? 64 + lane : lane - 32;
            segi[5] = 3;             offi[5] = 32 + lane;
#pragma unroll
            for (int i = 0; i < NSLOT; ++i)
                sv[i] = (offi[i] < wc[segi[i]]) ? list[SEG * segi[i] + offi[i]]
                                                : 0xFFFFFFFFu;
        }

        // MSB-first ballot radix select, 2 bits per round (11 rounds)
        uint32_t p = 0;
#pragma unroll
        for (int rb = SELBITS - 2; rb >= 0; rb -= 2) {
            const uint32_t m1 = p | (1u << rb);
            const uint32_t m2 = p | (2u << rb);
            const uint32_t m3 = p | (3u << rb);
            uint32_t n1 = 0, n2 = 0, n3 = 0;
#pragma unroll
            for (int i = 0; i < NSLOT; ++i) {
                n1 += (uint32_t)__popcll(__ballot(sv[i] < m1));
                n2 += (uint32_t)__popcll(__ballot(sv[i] < m2));
                n3 += (uint32_t)__popcll(__ballot(sv[i] < m3));
            }
            if (n3 <= r)      p = m3;   // wave-uniform
            else if (n2 <= r) p = m2;
            else if (n1 <= r) p = m1;
        }
        const float th = __uint_as_float(LOu + p);  // exact bits of theta

#pragma unroll
        for (int j = 0; j < 4; ++j) {
            float4 o;
            o.x = (f[4*j]   >= th) ? f[4*j]   : 0.0f;
            o.y = (f[4*j+1] >= th) ? f[4*j+1] : 0.0f;
            o.z = (f[4*j+2] >= th) ? f[4*j+2] : 0.0f;
            o.w = (f[4*j+3] >= th) ? f[4*j+3] : 0.0f;
            Ov[j * 256 + t] = o;
        }
    } else {
        // exact block-wide fallback (<1 row/dataset): 32-bit MSB bit-search
        uint32_t p = 0;
#pragma unroll 1
        for (int b = 31; b >= 0; --b) {
            const uint32_t mid = p | (1u << b);
            uint32_t cw = 0;
#pragma unroll
            for (int e = 0; e < 16; ++e)
                cw += (uint32_t)__popcll(__ballot(flipu(__float_as_uint(f[e])) < mid));
            if (lane == 0) fbc[w] = cw;
            lds_barrier();
            const uint32_t cm = fbc[0] + fbc[1] + fbc[2] + fbc[3];
            if (cm <= k) p = mid;   // block-uniform
            lds_barrier();          // fbc consumed before next overwrite
        }
#pragma unroll
        for (int j = 0; j < 4; ++j) {
            float4 o;
            o.x = (flipu(__float_as_uint(f[4*j]))   >= p) ? f[4*j]   : 0.0f;
            o.y = (flipu(__float_as_uint(f[4*j+1])) >= p) ? f[4*j+1] : 0.0f;
            o.z = (flipu(__float_as_uint(f[4*j+2])) >= p) ? f[4*j+2] : 0.0f;
            o.w = (flipu(__float_as_uint(f[4*j+3])) >= p) ? f[4*j+3] : 0.0f;
            Ov[j * 256 + t] = o;
        }
    }
}

extern "C" void kernel_launch(void* const* d_in, const int* in_sizes, int n_in,
                              void* d_out, int out_size, void* d_ws, size_t ws_size,
                              hipStream_t stream) {
    const float* X = (const float*)d_in[0];
    float* out = (float*)d_out;
    const int rows = in_sizes[0] / UNITS;
    const int kidx = (int)(0.7 * UNITS);  // 2867
    ksparse_select_kernel<<<rows, 256, 0, stream>>>(X, out, kidx);
}

// Round 12
// 85.837 us; speedup vs baseline: 1.1785x; 1.1785x over previous
//
#include <hip/hip_runtime.h>
#include <stdint.h>

#define UNITS  4096
#define SEG    96         // per-wave list segment; wave window count 60.5 +- 7.55 -> +4.8 sigma
#define CAP    (4 * SEG)  // 384
#define NSLOT  6          // CAP/64
#define LOF    0.44f      // theta ~= 0.5244 +- 0.0206 ; [LO,HI) = +-4.1 sigma
#define HIF    0.61f
#define SELBITS 22        // bits(0.61f)-bits(0.44f) = 0x3AE148 < 2^22

typedef float v4f __attribute__((ext_vector_type(4)));  // native vec for nt builtins

// LDS-only barrier (no vmcnt drain)
__device__ __forceinline__ void lds_barrier() {
    asm volatile("s_waitcnt lgkmcnt(0)" ::: "memory");
    __builtin_amdgcn_s_barrier();
}
__device__ __forceinline__ uint32_t flipu(uint32_t b) {
    return b ^ (uint32_t)(((int32_t)b >> 31) | (int32_t)0x80000000);
}
// popcount of mask bits strictly below this lane
__device__ __forceinline__ uint32_t mbcnt64(uint64_t m) {
    return __builtin_amdgcn_mbcnt_hi((uint32_t)(m >> 32),
           __builtin_amdgcn_mbcnt_lo((uint32_t)m, 0u));
}
// non-temporal 16B store: output is write-once/never-reread -> don't let it
// evict X from L2/L3 (X is re-read every replay; L3 retention is the win)
__device__ __forceinline__ void nt_store4(float* p, float a, float b, float c, float d) {
    v4f v = {a, b, c, d};
    __builtin_nontemporal_store(v, (v4f*)p);
}

// One block (256 threads) per row.
// Single fused pass: window ballots + scatter into per-wave fixed segments
// (no atomics). ONE barrier. All 4 waves redundantly radix-select rank
// (k - cb) over rebased 22-bit keys, 2 bits/round. Bracket + overflow checked
// per row; failures take the exact block-wide 32-bit bit-search fallback.
__global__ __launch_bounds__(256, 8) void ksparse_select_kernel(
        const float* __restrict__ X, float* __restrict__ out, int kidx) {
    __shared__ uint32_t list[CAP];  // 1.5 KiB, segmented per wave
    __shared__ uint32_t wnb[4];     // per-wave count below LO
    __shared__ uint32_t wc[4];      // per-wave window count (may exceed SEG)
    __shared__ uint32_t fbc[4];     // fallback per-wave counts

    const int t    = threadIdx.x;
    const int w    = t >> 6;
    const int lane = t & 63;

    // load row (coalesced float4) — NORMAL loads: X wants L3 residency
    float f[16];
    {
        const float4* Xv = reinterpret_cast<const float4*>(X + (size_t)blockIdx.x * UNITS);
#pragma unroll
        for (int j = 0; j < 4; ++j) {
            float4 v = Xv[j * 256 + t];
            f[4*j] = v.x; f[4*j+1] = v.y; f[4*j+2] = v.z; f[4*j+3] = v.w;
        }
    }

    // fused window-count + segment scatter (single pass, no atomics)
    const uint32_t LOu = __float_as_uint(LOF);
    uint32_t nbw = 0, pfx = 0;
#pragma unroll
    for (int e = 0; e < 16; ++e) {
        const bool lo = f[e] < LOF;
        const bool hi = f[e] < HIF;
        const uint64_t mlo  = __ballot(lo);
        const uint64_t mwin = __ballot(hi && !lo);
        nbw += (uint32_t)__popcll(mlo);
        if (hi && !lo) {
            const uint32_t off = pfx + mbcnt64(mwin);
            if (off < SEG) list[SEG * w + off] = __float_as_uint(f[e]) - LOu;
        }
        pfx += (uint32_t)__popcll(mwin);
    }
    if (lane == 0) { wnb[w] = nbw; wc[w] = pfx; }

    lds_barrier();  // list + wnb + wc visible (the ONLY fast-path barrier)

    const uint32_t c0 = wc[0], c1 = wc[1], c2 = wc[2], c3 = wc[3];
    const uint32_t c  = c0 + c1 + c2 + c3;
    const uint32_t cb = wnb[0] + wnb[1] + wnb[2] + wnb[3];
    const uint32_t k  = (uint32_t)kidx;
    const uint32_t mx = max(max(c0, c1), max(c2, c3));

    float* Ob = out + (size_t)blockIdx.x * UNITS;

    if (cb <= k && k < cb + c && mx <= SEG) {   // block-uniform bracket check
        const uint32_t r = k - cb;              // rank of theta within the window

        // distributed list load, static (seg, off) map per slot, sentinel-padded
        uint32_t sv[NSLOT];
        {
            const bool loh = lane < 32;
            uint32_t segi[NSLOT], offi[NSLOT];
            segi[0] = 0;             offi[0] = lane;
            segi[1] = loh ? 0 : 1;   offi[1] = loh ? 64 + lane : lane - 32;
            segi[2] = 1;             offi[2] = 32 + lane;
            segi[3] = 2;             offi[3] = lane;
            segi[4] = loh ? 2 : 3;   offi[4] = loh ? 64 + lane : lane - 32;
            segi[5] = 3;             offi[5] = 32 + lane;
#pragma unroll
            for (int i = 0; i < NSLOT; ++i)
                sv[i] = (offi[i] < wc[segi[i]]) ? list[SEG * segi[i] + offi[i]]
                                                : 0xFFFFFFFFu;
        }

        // MSB-first ballot radix select, 2 bits per round (11 rounds)
        uint32_t p = 0;
#pragma unroll
        for (int rb = SELBITS - 2; rb >= 0; rb -= 2) {
            const uint32_t m1 = p | (1u << rb);
            const uint32_t m2 = p | (2u << rb);
            const uint32_t m3 = p | (3u << rb);
            uint32_t n1 = 0, n2 = 0, n3 = 0;
#pragma unroll
            for (int i = 0; i < NSLOT; ++i) {
                n1 += (uint32_t)__popcll(__ballot(sv[i] < m1));
                n2 += (uint32_t)__popcll(__ballot(sv[i] < m2));
                n3 += (uint32_t)__popcll(__ballot(sv[i] < m3));
            }
            if (n3 <= r)      p = m3;   // wave-uniform
            else if (n2 <= r) p = m2;
            else if (n1 <= r) p = m1;
        }
        const float th = __uint_as_float(LOu + p);  // exact bits of theta

#pragma unroll
        for (int j = 0; j < 4; ++j) {
            nt_store4(Ob + 4 * (j * 256 + t),
                      (f[4*j]   >= th) ? f[4*j]   : 0.0f,
                      (f[4*j+1] >= th) ? f[4*j+1] : 0.0f,
                      (f[4*j+2] >= th) ? f[4*j+2] : 0.0f,
                      (f[4*j+3] >= th) ? f[4*j+3] : 0.0f);
        }
    } else {
        // exact block-wide fallback (<1 row/dataset): 32-bit MSB bit-search
        uint32_t p = 0;
#pragma unroll 1
        for (int b = 31; b >= 0; --b) {
            const uint32_t mid = p | (1u << b);
            uint32_t cw = 0;
#pragma unroll
            for (int e = 0; e < 16; ++e)
                cw += (uint32_t)__popcll(__ballot(flipu(__float_as_uint(f[e])) < mid));
            if (lane == 0) fbc[w] = cw;
            lds_barrier();
            const uint32_t cm = fbc[0] + fbc[1] + fbc[2] + fbc[3];
            if (cm <= k) p = mid;   // block-uniform
            lds_barrier();          // fbc consumed before next overwrite
        }
#pragma unroll
        for (int j = 0; j < 4; ++j) {
            nt_store4(Ob + 4 * (j * 256 + t),
                      (flipu(__float_as_uint(f[4*j]))   >= p) ? f[4*j]   : 0.0f,
                      (flipu(__float_as_uint(f[4*j+1])) >= p) ? f[4*j+1] : 0.0f,
                      (flipu(__float_as_uint(f[4*j+2])) >= p) ? f[4*j+2] : 0.0f,
                      (flipu(__float_as_uint(f[4*j+3])) >= p) ? f[4*j+3] : 0.0f);
        }
    }
}

extern "C" void kernel_launch(void* const* d_in, const int* in_sizes, int n_in,
                              void* d_out, int out_size, void* d_ws, size_t ws_size,
                              hipStream_t stream) {
    const float* X = (const float*)d_in[0];
    float* out = (float*)d_out;
    const int rows = in_sizes[0] / UNITS;
    const int kidx = (int)(0.7 * UNITS);  // 2867
    ksparse_select_kernel<<<rows, 256, 0, stream>>>(X, out, kidx);
}